// Round 1
// baseline (144.125 us; speedup 1.0000x reference)
//
#include <hip/hip_runtime.h>
#include <stdint.h>

#define NN 16384
#define MM 16384
#define DD 8
#define DV 16
#define WAVES 4
#define MT 2                        // 16-row m-tiles per wave
#define ROWS_WAVE (MT * 16)         // 32
#define ROWS_BLK (WAVES * ROWS_WAVE)// 128
#define JSPLIT 32
#define JCHUNK (MM / JSPLIT)        // 512
#define J32 (JCHUNK / 32)           // 16 iterations per block

typedef short bf8 __attribute__((ext_vector_type(8)));   // 8 bf16 (4 VGPR)
typedef float f32x2 __attribute__((ext_vector_type(2))); // VOP3P packed pair
typedef float f32x4 __attribute__((ext_vector_type(4))); // MFMA C/D

#define C3SQ 10.406844905028037f     /* 5*log2(e)^2 : folded into tables */
#define C2S  (1.2909944487358056f / 10.406844905028037f)  /* c2/c3sq */
#define LN2  0.6931471805599453f

__device__ __forceinline__ unsigned short f2bf(float f) {
    union { float f; uint32_t u; } c; c.f = f;
    uint32_t u = c.u + 0x7FFF + ((c.u >> 16) & 1);       // RNE
    return (unsigned short)(u >> 16);
}
__device__ __forceinline__ float bf2f(unsigned short h) {
    union { float f; uint32_t u; } c; c.u = ((uint32_t)h) << 16;
    return c.f;
}

#define BF16_ONE ((short)0x3F80)

// Tables with the SCALED d2 fold: MFMA emits z = c3sq*d2 directly.
//   quads 0..2 of B hold w = -2*c3sq*y (split hi,hi,lo AFTER fp32 scaling)
//   quad 3: A {1,1,csx_hi,csx_lo} x B {csy_hi,csy_lo,1,1}, c* = c3sq-scaled
// btbl K-order PERMUTED to match interleaved klds columns:
//   k -> j_local = (k>>1) + ((k&1)<<4)
__global__ __launch_bounds__(256) void prep_frags(const float* __restrict__ ls,
                                                  const float* __restrict__ y,
                                                  const float* __restrict__ b,
                                                  bf8* __restrict__ ytbl,
                                                  bf8* __restrict__ btbl,
                                                  float4* __restrict__ outz) {
    const int tile = blockIdx.x * 4 + (threadIdx.x >> 6);  // 0..1023 (j16 tiles)
    const int lane = threadIdx.x & 63;
    const int n = lane & 15, quad = lane >> 4;

    // zero d_out: 256 blocks * 256 threads * 16B = 1 MB
    outz[blockIdx.x * 256 + threadIdx.x] = make_float4(0.f, 0.f, 0.f, 0.f);

    float lsv[DD];
#pragma unroll
    for (int d = 0; d < DD; ++d) lsv[d] = ls[d];

    const float4* yr4 = (const float4*)(y + (size_t)(tile * 16 + n) * DD);
    float4 ya = yr4[0], yb = yr4[1];
    float yv[DD] = {ya.x, ya.y, ya.z, ya.w, yb.x, yb.y, yb.z, yb.w};

    float syv = 0.f;
    unsigned short wh[DD], wl[DD];
#pragma unroll
    for (int d = 0; d < DD; ++d) {
        syv = fmaf(lsv[d] * yv[d], yv[d], syv);
        float w = -2.f * C3SQ * yv[d];          // scale in fp32, THEN split
        wh[d] = f2bf(w);
        wl[d] = f2bf(w - bf2f(wh[d]));
    }

    bf8 fr;
    if (quad < 3) {
#pragma unroll
        for (int d = 0; d < DD; ++d)
            fr[d] = (short)((quad == 2) ? wl[d] : wh[d]);
    } else {
        float csy = C3SQ * syv;
        unsigned short sh = f2bf(csy);
        unsigned short sl = f2bf(csy - bf2f(sh));
        fr[0] = (short)sh;      // k=24: 1 * csy_hi
        fr[1] = (short)sl;      // k=25: 1 * csy_lo
        fr[2] = BF16_ONE;       // k=26: csx_hi * 1
        fr[3] = BF16_ONE;       // k=27: csx_lo * 1
        fr[4] = 0; fr[5] = 0; fr[6] = 0; fr[7] = 0;
    }
    ytbl[tile * 64 + lane] = fr;

    if (tile < MM / 32) {             // j32 tiles for phase B, PERMUTED K-order
        bf8 bfr;
#pragma unroll
        for (int s = 0; s < 8; ++s) {
            int k = quad * 8 + s;
            int jl = (k >> 1) + ((k & 1) << 4);   // interleaved klds col -> j
            float bv = b[(size_t)(tile * 32 + jl) * DV + n];
            bfr[s] = (short)f2bf(bv);
        }
        btbl[tile * 64 + lane] = bfr;
    }
}

// R13: VOP3P-packed transform + 1-deep table prefetch.
//  - transform math paired (s0[s],s1[s]) as float2: v_pk_max (abs->clamp0),
//    2x v_pk_fma, v_pk_mul -- halves full-rate VALU around the transcendentals
//  - bf16 pack: 2x v_add_u32 + 1x v_perm_b32 (round-half-up, k>0), replaces
//    the conditional cvt_pk/scalar-fallback path deterministically
//  - ytbl/btbl loads prefetched one J32-iteration ahead (register rotation),
//    hiding ~200cy L2 latency that showed as the 26% non-issue gap
//  - NO inline asm (R6-R8 culprit), NO barriers (klds is per-wave)
__global__ __launch_bounds__(256, 8) void matern_mfma(const float* __restrict__ ls,
                                                      const float* __restrict__ x,
                                                      const bf8* __restrict__ ytbl,
                                                      const bf8* __restrict__ btbl,
                                                      float* __restrict__ out) {
    const int t = threadIdx.x;
    const int lane = t & 63, wave = t >> 6;
    const int n = lane & 15, quad = lane >> 4;
    const int waverow = blockIdx.x * ROWS_BLK + wave * ROWS_WAVE;

    // [wave][mt][m][40]: 80B rows; b32 writes (20*row+n)%32 -> 2-way free;
    // b128 reads 16B-aligned, 2-way free (R5-proven).
    __shared__ __attribute__((aligned(16))) unsigned short klds[WAVES][MT][16][40];

    float lsv[DD];
#pragma unroll
    for (int d = 0; d < DD; ++d) lsv[d] = ls[d];

    // A-frags: quad 0/2 -> xls_hi, quad 1 -> xls_lo, quad 3 -> {1,1,csx_hi,csx_lo}
    bf8 afrag[MT];
#pragma unroll
    for (int mt = 0; mt < MT; ++mt) {
        const float* xr = x + (size_t)(waverow + mt * 16 + n) * DD;
        float sx = 0.f;
        unsigned short xh[DD], xl[DD];
#pragma unroll
        for (int d = 0; d < DD; ++d) {
            float xv = xr[d];
            float xlsv = lsv[d] * xv;
            sx = fmaf(xlsv, xv, sx);
            xh[d] = f2bf(xlsv);
            xl[d] = f2bf(xlsv - bf2f(xh[d]));
        }
        bf8 fr;
        if (quad == 3) {
            float csx = C3SQ * sx;               // scale in fp32, THEN split
            unsigned short sh = f2bf(csx);
            unsigned short sl = f2bf(csx - bf2f(sh));
            fr[0] = BF16_ONE;   // k=24: 1 * csy_hi
            fr[1] = BF16_ONE;   // k=25: 1 * csy_lo
            fr[2] = (short)sh;  // k=26: csx_hi * 1
            fr[3] = (short)sl;  // k=27: csx_lo * 1
            fr[4] = 0; fr[5] = 0; fr[6] = 0; fr[7] = 0;
        } else {
#pragma unroll
            for (int d = 0; d < DD; ++d)
                fr[d] = (short)((quad == 1) ? xl[d] : xh[d]);
        }
        afrag[mt] = fr;
    }

    f32x4 acc[MT];
#pragma unroll
    for (int mt = 0; mt < MT; ++mt) acc[mt] = (f32x4){0.f, 0.f, 0.f, 0.f};

    const int tile16base = blockIdx.y * (JCHUNK / 16);
    const int tile32base = blockIdx.y * (JCHUNK / 32);

    const bf8* ybase = ytbl + (size_t)tile16base * 64 + lane;
    const bf8* bbase = btbl + (size_t)tile32base * 64 + lane;

    // prologue loads for it=0
    bf8 yA = ybase[0];
    bf8 yB = ybase[64];
    bf8 bb = bbase[0];

#pragma unroll 1
    for (int it = 0; it < J32; ++it) {
        // prefetch it+1 (wraps to 0 on last iter: in-chunk, cache-hot, safe)
        const int nx = (it + 1) & (J32 - 1);
        bf8 pyA = ybase[(size_t)nx * 128];
        bf8 pyB = ybase[(size_t)nx * 128 + 64];
        bf8 pbb = bbase[(size_t)nx * 64];

#pragma unroll
        for (int mt = 0; mt < MT; ++mt) {
            f32x4 z4 = (f32x4){0.f, 0.f, 0.f, 0.f};
            f32x4 s0 = __builtin_amdgcn_mfma_f32_16x16x32_bf16(afrag[mt], yA, z4, 0, 0, 0);
            f32x4 s1 = __builtin_amdgcn_mfma_f32_16x16x32_bf16(afrag[mt], yB, z4, 0, 0, 0);
#pragma unroll
            for (int s = 0; s < 4; ++s) {
                // s0/s1 ARE c3sq*d2; clamp-to-0 eats rounding-noise negatives
                // (z=0 -> k=1, the correct limit). Packed pair = VOP3P ops.
                f32x2 a = {s0[s], s1[s]};
                a = __builtin_elementwise_max(a, (f32x2){0.f, 0.f});      // v_pk_max_f32
                f32x2 tt = {__builtin_amdgcn_sqrtf(a[0]),                 // |c3|*r
                            __builtin_amdgcn_sqrtf(a[1])};
                f32x2 ee = {__builtin_amdgcn_exp2f(-tt[0]),               // neg = free mod
                            __builtin_amdgcn_exp2f(-tt[1])};
                f32x2 pp = __builtin_elementwise_fma(
                               (f32x2){C2S, C2S}, a,
                               __builtin_elementwise_fma((f32x2){LN2, LN2}, tt,
                                                         (f32x2){1.f, 1.f}));  // 2x v_pk_fma_f32
                f32x2 kk = pp * ee;                                       // v_pk_mul_f32
                // bf16 round-half-up (k>0) + byte-perm pack: 3 VALU ops total
                unsigned int u0 = __float_as_uint(kk[0]) + 0x8000u;
                unsigned int u1 = __float_as_uint(kk[1]) + 0x8000u;
                // dst = {hi16(u1), hi16(u0)}: cols 2n (tile0) / 2n+1 (tile1)
                *(unsigned int*)&klds[wave][mt][quad * 4 + s][2 * n] =
                    __builtin_amdgcn_perm(u1, u0, 0x07060302u);           // v_perm_b32
            }
        }
        // C/D->A: lane reads A'[m=lane&15][k=quad*8+s] as one 16B LDS read;
        // interleaved cols match btbl's permuted K-order.
#pragma unroll
        for (int mt = 0; mt < MT; ++mt) {
            const bf8* kp = (const bf8*)&klds[wave][mt][n][quad * 8];
            acc[mt] = __builtin_amdgcn_mfma_f32_16x16x32_bf16(*kp, bb, acc[mt], 0, 0, 0);
        }
        // rotate prefetched registers (12 v_mov/iter, ~2% of body)
        yA = pyA; yB = pyB; bb = pbb;
    }

    // Epilogue: D layout row=quad*4+s, col=n; JSPLIT partial sums via atomics
#pragma unroll
    for (int mt = 0; mt < MT; ++mt)
#pragma unroll
        for (int s = 0; s < 4; ++s) {
            const int row = waverow + mt * 16 + quad * 4 + s;
            atomicAdd(out + (size_t)row * DV + n, acc[mt][s]);
        }
}

extern "C" void kernel_launch(void* const* d_in, const int* in_sizes, int n_in,
                              void* d_out, int out_size, void* d_ws, size_t ws_size,
                              hipStream_t stream) {
    const float* ls = (const float*)d_in[0];
    const float* x  = (const float*)d_in[1];
    const float* y  = (const float*)d_in[2];
    const float* b  = (const float*)d_in[3];
    float* out = (float*)d_out;

    char* ws = (char*)d_ws;
    bf8* ytbl = (bf8*)ws;                        // 1024*64*16B = 1 MB
    bf8* btbl = (bf8*)(ws + (1 << 20));          // 512*64*16B  = 512 KB

    prep_frags<<<MM / 64, 256, 0, stream>>>(ls, y, b, ytbl, btbl, (float4*)out);
    matern_mfma<<<dim3(NN / ROWS_BLK, JSPLIT), 256, 0, stream>>>(ls, x, ytbl, btbl, out);
}

// Round 2
// 136.406 us; speedup vs baseline: 1.0566x; 1.0566x over previous
//
#include <hip/hip_runtime.h>
#include <stdint.h>

#define NN 16384
#define MM 16384
#define DD 8
#define DV 16
#define WAVES 4
#define MT 2                        // 16-row m-tiles per wave
#define ROWS_WAVE (MT * 16)         // 32
#define ROWS_BLK (WAVES * ROWS_WAVE)// 128
#define JSPLIT 32
#define JCHUNK (MM / JSPLIT)        // 512
#define J32 (JCHUNK / 32)           // 16 iterations per block

typedef short bf8 __attribute__((ext_vector_type(8)));   // 8 bf16 (4 VGPR)
typedef short s2v __attribute__((ext_vector_type(2)));   // 2 bf16, one b32 store
typedef float f32x4 __attribute__((ext_vector_type(4))); // MFMA C/D

#define C3SQ 10.406844905028037f     /* 5*log2(e)^2 : folded into tables */
#define C2S  (1.2909944487358056f / 10.406844905028037f)  /* c2/c3sq */
#define LN2  0.6931471805599453f

// PWL table for k(z) = (1 + LN2*t + C2S*z) * 2^-t, t = sqrt(z).
// Log-spaced segments via float bits: exponent range 2^-8 .. 2^10,
// 32 segments/octave (top-5 mantissa bits). 18 octaves * 32 = 576 entries.
// idx = (bits(z) >> 18) - (119<<5), clamped. Interp error <= ~6e-6,
// far below the bf16 rounding (2^-9) already applied to k.
#define KTAB_N 576
#define KTAB_SHIFT 18
#define KTAB_OFS 3808   /* (127-8) << 5 */

__device__ __forceinline__ unsigned short f2bf(float f) {
    union { float f; uint32_t u; } c; c.f = f;
    uint32_t u = c.u + 0x7FFF + ((c.u >> 16) & 1);       // RNE
    return (unsigned short)(u >> 16);
}
__device__ __forceinline__ float bf2f(unsigned short h) {
    union { float f; uint32_t u; } c; c.u = ((uint32_t)h) << 16;
    return c.f;
}

#define BF16_ONE ((short)0x3F80)

// Tables with the SCALED d2 fold: MFMA emits z = c3sq*d2 directly.
//   quads 0..2 of B hold w = -2*c3sq*y (split hi,hi,lo AFTER fp32 scaling)
//   quad 3: A {1,1,csx_hi,csx_lo} x B {csy_hi,csy_lo,1,1}, c* = c3sq-scaled
// btbl K-order PERMUTED to match interleaved klds columns:
//   k -> j_local = (k>>1) + ((k&1)<<4)
__global__ __launch_bounds__(256) void prep_frags(const float* __restrict__ ls,
                                                  const float* __restrict__ y,
                                                  const float* __restrict__ b,
                                                  bf8* __restrict__ ytbl,
                                                  bf8* __restrict__ btbl,
                                                  float4* __restrict__ outz) {
    const int tile = blockIdx.x * 4 + (threadIdx.x >> 6);  // 0..1023 (j16 tiles)
    const int lane = threadIdx.x & 63;
    const int n = lane & 15, quad = lane >> 4;

    // zero d_out: 256 blocks * 256 threads * 16B = 1 MB
    outz[blockIdx.x * 256 + threadIdx.x] = make_float4(0.f, 0.f, 0.f, 0.f);

    float lsv[DD];
#pragma unroll
    for (int d = 0; d < DD; ++d) lsv[d] = ls[d];

    const float4* yr4 = (const float4*)(y + (size_t)(tile * 16 + n) * DD);
    float4 ya = yr4[0], yb = yr4[1];
    float yv[DD] = {ya.x, ya.y, ya.z, ya.w, yb.x, yb.y, yb.z, yb.w};

    float syv = 0.f;
    unsigned short wh[DD], wl[DD];
#pragma unroll
    for (int d = 0; d < DD; ++d) {
        syv = fmaf(lsv[d] * yv[d], yv[d], syv);
        float w = -2.f * C3SQ * yv[d];          // scale in fp32, THEN split
        wh[d] = f2bf(w);
        wl[d] = f2bf(w - bf2f(wh[d]));
    }

    bf8 fr;
    if (quad < 3) {
#pragma unroll
        for (int d = 0; d < DD; ++d)
            fr[d] = (short)((quad == 2) ? wl[d] : wh[d]);
    } else {
        float csy = C3SQ * syv;
        unsigned short sh = f2bf(csy);
        unsigned short sl = f2bf(csy - bf2f(sh));
        fr[0] = (short)sh;      // k=24: 1 * csy_hi
        fr[1] = (short)sl;      // k=25: 1 * csy_lo
        fr[2] = BF16_ONE;       // k=26: csx_hi * 1
        fr[3] = BF16_ONE;       // k=27: csx_lo * 1
        fr[4] = 0; fr[5] = 0; fr[6] = 0; fr[7] = 0;
    }
    ytbl[tile * 64 + lane] = fr;

    if (tile < MM / 32) {             // j32 tiles for phase B, PERMUTED K-order
        bf8 bfr;
#pragma unroll
        for (int s = 0; s < 8; ++s) {
            int k = quad * 8 + s;
            int jl = (k >> 1) + ((k & 1) << 4);   // interleaved klds col -> j
            float bv = b[(size_t)(tile * 32 + jl) * DV + n];
            bfr[s] = (short)f2bf(bv);
        }
        btbl[tile * 64 + lane] = bfr;
    }
}

// R14 = R12 structure (proven 88us) with the transform moved OFF the trans
// unit: sqrt+exp2 (32 trans/iter ~= 70% of VALU-pipe cycles, back-solved
// from VALUBusy=74%) replaced by a 576-entry PWL LDS table gathered with
// ds_read_b64 (DS pipe was idle). Per element: max + shr/sub/clamp + gather
// + 1 fma. R13's VOP3P/prefetch experiment reverted (regressed: elementwise
// builtins scalarized, pack path lost cvt_pk).
__global__ __launch_bounds__(256, 8) void matern_mfma(const float* __restrict__ ls,
                                                      const float* __restrict__ x,
                                                      const bf8* __restrict__ ytbl,
                                                      const bf8* __restrict__ btbl,
                                                      float* __restrict__ out) {
    const int t = threadIdx.x;
    const int lane = t & 63, wave = t >> 6;
    const int n = lane & 15, quad = lane >> 4;
    const int waverow = blockIdx.x * ROWS_BLK + wave * ROWS_WAVE;

    // [wave][mt][m][40]: 80B rows; b32 writes (20*row+n)%32 -> 2-way free;
    // b128 reads 16B-aligned, 2-way free (R5-proven).
    __shared__ __attribute__((aligned(16))) unsigned short klds[WAVES][MT][16][40];
    __shared__ __attribute__((aligned(16))) float2 ktab[KTAB_N];

    // Build the PWL table (once per block, ~3 entries/thread, trivial cost).
    for (int i = t; i < KTAB_N; i += 256) {
        uint32_t b0 = ((uint32_t)(i + KTAB_OFS)) << KTAB_SHIFT;   // left edge bits
        float z0 = __uint_as_float(b0);
        float z1 = __uint_as_float(b0 + (1u << KTAB_SHIFT));      // right edge
        float t0 = __builtin_amdgcn_sqrtf(z0);
        float t1 = __builtin_amdgcn_sqrtf(z1);
        float k0 = fmaf(C2S, z0, fmaf(LN2, t0, 1.f)) * __builtin_amdgcn_exp2f(-t0);
        float k1 = fmaf(C2S, z1, fmaf(LN2, t1, 1.f)) * __builtin_amdgcn_exp2f(-t1);
        float S = (k1 - k0) / (z1 - z0);
        float B = fmaf(-S, z0, k0);
        if (i == KTAB_N - 1) { S = 0.f; B = 0.f; }   // z >= 2^10: k ~ 2^-32 -> 0
        ktab[i] = make_float2(B, S);
    }
    __syncthreads();   // table read-only hereafter; klds stays per-wave

    float lsv[DD];
#pragma unroll
    for (int d = 0; d < DD; ++d) lsv[d] = ls[d];

    // A-frags: quad 0/2 -> xls_hi, quad 1 -> xls_lo, quad 3 -> {1,1,csx_hi,csx_lo}
    bf8 afrag[MT];
#pragma unroll
    for (int mt = 0; mt < MT; ++mt) {
        const float* xr = x + (size_t)(waverow + mt * 16 + n) * DD;
        float sx = 0.f;
        unsigned short xh[DD], xl[DD];
#pragma unroll
        for (int d = 0; d < DD; ++d) {
            float xv = xr[d];
            float xlsv = lsv[d] * xv;
            sx = fmaf(xlsv, xv, sx);
            xh[d] = f2bf(xlsv);
            xl[d] = f2bf(xlsv - bf2f(xh[d]));
        }
        bf8 fr;
        if (quad == 3) {
            float csx = C3SQ * sx;               // scale in fp32, THEN split
            unsigned short sh = f2bf(csx);
            unsigned short sl = f2bf(csx - bf2f(sh));
            fr[0] = BF16_ONE;   // k=24: 1 * csy_hi
            fr[1] = BF16_ONE;   // k=25: 1 * csy_lo
            fr[2] = (short)sh;  // k=26: csx_hi * 1
            fr[3] = (short)sl;  // k=27: csx_lo * 1
            fr[4] = 0; fr[5] = 0; fr[6] = 0; fr[7] = 0;
        } else {
#pragma unroll
            for (int d = 0; d < DD; ++d)
                fr[d] = (short)((quad == 1) ? xl[d] : xh[d]);
        }
        afrag[mt] = fr;
    }

    f32x4 acc[MT];
#pragma unroll
    for (int mt = 0; mt < MT; ++mt) acc[mt] = (f32x4){0.f, 0.f, 0.f, 0.f};

    const int tile16base = blockIdx.y * (JCHUNK / 16);
    const int tile32base = blockIdx.y * (JCHUNK / 32);

#pragma unroll 1
    for (int it = 0; it < J32; ++it) {
        const int tl0 = tile16base + it * 2;
        bf8 yA = ytbl[(size_t)tl0 * 64 + lane];
        bf8 yB = ytbl[(size_t)(tl0 + 1) * 64 + lane];
        bf8 bb = btbl[(size_t)(tile32base + it) * 64 + lane];

#pragma unroll
        for (int mt = 0; mt < MT; ++mt) {
            f32x4 z4 = (f32x4){0.f, 0.f, 0.f, 0.f};
            f32x4 s0 = __builtin_amdgcn_mfma_f32_16x16x32_bf16(afrag[mt], yA, z4, 0, 0, 0);
            f32x4 s1 = __builtin_amdgcn_mfma_f32_16x16x32_bf16(afrag[mt], yB, z4, 0, 0, 0);
#pragma unroll
            for (int s = 0; s < 4; ++s) {
                // s0/s1 ARE c3sq*d2; clamp-to-0 eats rounding-noise negatives
                // (idx 0 -> k ~ 1, the correct limit).
                float z0c = fmaxf(s0[s], 0.f);
                float z1c = fmaxf(s1[s], 0.f);
                int i0 = (int)(__float_as_uint(z0c) >> KTAB_SHIFT) - KTAB_OFS;
                int i1 = (int)(__float_as_uint(z1c) >> KTAB_SHIFT) - KTAB_OFS;
                i0 = i0 < 0 ? 0 : (i0 > KTAB_N - 1 ? KTAB_N - 1 : i0);
                i1 = i1 < 0 ? 0 : (i1 > KTAB_N - 1 ? KTAB_N - 1 : i1);
                float2 e0 = ktab[i0];            // ds_read_b64 gather
                float2 e1 = ktab[i1];
                float k0 = fmaf(e0.y, z0c, e0.x);
                float k1 = fmaf(e1.y, z1c, e1.x);
                s2v w;
#if __has_builtin(__builtin_amdgcn_cvt_pk_bf16_f32)
                typedef __bf16 bf2v __attribute__((ext_vector_type(2)));
                bf2v pk = __builtin_amdgcn_cvt_pk_bf16_f32(k0, k1);
                union { bf2v v; s2v s; } cv; cv.v = pk;
                w = cv.s;
#else
                // round-half-up bf16 (k>=0): proven 2-op path per value
                w[0] = (short)((__float_as_uint(k0) + 0x8000u) >> 16);
                w[1] = (short)((__float_as_uint(k1) + 0x8000u) >> 16);
#endif
                // one b32 store: cols 2n (tile0) / 2n+1 (tile1), interleaved
                *(s2v*)&klds[wave][mt][quad * 4 + s][2 * n] = w;
            }
        }
        // C/D->A: lane reads A'[m=lane&15][k=quad*8+s] as one 16B LDS read;
        // interleaved cols match btbl's permuted K-order.
#pragma unroll
        for (int mt = 0; mt < MT; ++mt) {
            const bf8* kp = (const bf8*)&klds[wave][mt][n][quad * 8];
            acc[mt] = __builtin_amdgcn_mfma_f32_16x16x32_bf16(*kp, bb, acc[mt], 0, 0, 0);
        }
    }

    // Epilogue: D layout row=quad*4+s, col=n; JSPLIT partial sums via atomics
#pragma unroll
    for (int mt = 0; mt < MT; ++mt)
#pragma unroll
        for (int s = 0; s < 4; ++s) {
            const int row = waverow + mt * 16 + quad * 4 + s;
            atomicAdd(out + (size_t)row * DV + n, acc[mt][s]);
        }
}

extern "C" void kernel_launch(void* const* d_in, const int* in_sizes, int n_in,
                              void* d_out, int out_size, void* d_ws, size_t ws_size,
                              hipStream_t stream) {
    const float* ls = (const float*)d_in[0];
    const float* x  = (const float*)d_in[1];
    const float* y  = (const float*)d_in[2];
    const float* b  = (const float*)d_in[3];
    float* out = (float*)d_out;

    char* ws = (char*)d_ws;
    bf8* ytbl = (bf8*)ws;                        // 1024*64*16B = 1 MB
    bf8* btbl = (bf8*)(ws + (1 << 20));          // 512*64*16B  = 512 KB

    prep_frags<<<MM / 64, 256, 0, stream>>>(ls, y, b, ytbl, btbl, (float4*)out);
    matern_mfma<<<dim3(NN / ROWS_BLK, JSPLIT), 256, 0, stream>>>(ls, x, ytbl, btbl, out);
}